// Round 2
// baseline (739.838 us; speedup 1.0000x reference)
//
#include <hip/hip_runtime.h>
#include <math.h>

// Problem constants (match reference)
#define N_ROWS   16384            // 32*512
#define DIM      64
#define K_CODES  8192
#define SPLITS   16
#define KC       (K_CODES / SPLITS)   // 512 codes per split
#define BR       256                  // rows per argmin block (1 per thread)
#define RB       (N_ROWS / BR)        // 64 row-blocks

// Output layout (flat float32): loss | quantized | perplexity | encodings
#define OFF_LOSS 0
#define OFF_Q    1
#define OFF_P    1048577
#define OFF_E    1048578
#define ZBASE    1048576              // 16B-aligned base for bulk zero-fill
#define ENC_F4_TOTAL 33554432ULL      // 134217728 floats / 4
#define NBLOCKS  (RB * SPLITS)        // 1024
#define ZF4_PER_BLOCK (ENC_F4_TOTAL / NBLOCKS)      // 32768 float4 per block
#define ZSTORES_PER_THREAD (ZF4_PER_BLOCK / 256)    // 128 per thread

// native clang vector type (works with __builtin_nontemporal_store)
typedef float vfloat4 __attribute__((ext_vector_type(4)));

// Workspace layout (bytes)
#define WS_E2    0                    // 8192 floats
#define WS_MIND  32768                // SPLITS*N floats = 1 MiB
#define WS_MIDX  (32768 + 1048576)    // SPLITS*N ints  = 1 MiB
#define WS_HIST  (32768 + 2097152)    // 8192 ints
#define WS_LOSS  (32768 + 2097152 + 32768)  // 1 float

// ---------------- codebook squared norms ----------------
__global__ __launch_bounds__(256) void vq_sqnorm_kernel(
    const float* __restrict__ cb, float* __restrict__ e2) {
  const int k = blockIdx.x * 256 + threadIdx.x;
  const float4* e = reinterpret_cast<const float4*>(cb + ((size_t)k << 6));
  float s0 = 0.f, s1 = 0.f, s2 = 0.f, s3 = 0.f;
#pragma unroll
  for (int i = 0; i < DIM / 4; ++i) {
    float4 v = e[i];
    s0 = fmaf(v.x, v.x, s0);
    s1 = fmaf(v.y, v.y, s1);
    s2 = fmaf(v.z, v.z, s2);
    s3 = fmaf(v.w, v.w, s3);
  }
  e2[k] = (s0 + s1) + (s2 + s3);
}

// ---------------- main argmin (split-K) + fused encodings zero-fill ----------------
__global__ __launch_bounds__(256, 2) void vq_argmin_kernel(
    const float* __restrict__ x, const float* __restrict__ cb,
    const float* __restrict__ e2, float* __restrict__ mind,
    int* __restrict__ midx, float* __restrict__ outp) {
  const int tid = threadIdx.x;
  const int rb  = blockIdx.x;   // row-block
  const int sp  = blockIdx.y;   // K split
  const int row = rb * BR + tid;
  const int blin = sp * gridDim.x + rb;

  // bulk zero-fill destination for this block (16B aligned: ZBASE*4 % 16 == 0)
  vfloat4* zdst = reinterpret_cast<vfloat4*>(outp + ZBASE) + (size_t)blin * ZF4_PER_BLOCK;
  if (blin == 0 && tid == 0) {
    // two tail floats not covered by the float4 bulk region
    outp[135266304] = 0.0f;
    outp[135266305] = 0.0f;
  }

  // whole input row in registers (64 VGPRs)
  float xr[DIM];
  const float4* xv = reinterpret_cast<const float4*>(x + ((size_t)row << 6));
#pragma unroll
  for (int i = 0; i < DIM / 4; ++i) reinterpret_cast<float4*>(xr)[i] = xv[i];

  float best = 3.4e38f;
  int bi = 0;
  const int k0 = sp * KC;
  const vfloat4 zz = (vfloat4)(0.0f);

  for (int it = 0; it < KC / 2; ++it) {
    const int k = k0 + it * 2;
    const float* __restrict__ e0 = cb + ((size_t)k << 6);
    const float* __restrict__ e1 = e0 + DIM;
    float a0 = 0.f, a1 = 0.f, a2 = 0.f, a3 = 0.f;
    float b0 = 0.f, b1 = 0.f, b2 = 0.f, b3 = 0.f;
#pragma unroll
    for (int d = 0; d < DIM; d += 4) {
      a0 = fmaf(xr[d + 0], e0[d + 0], a0);
      a1 = fmaf(xr[d + 1], e0[d + 1], a1);
      a2 = fmaf(xr[d + 2], e0[d + 2], a2);
      a3 = fmaf(xr[d + 3], e0[d + 3], a3);
      b0 = fmaf(xr[d + 0], e1[d + 0], b0);
      b1 = fmaf(xr[d + 1], e1[d + 1], b1);
      b2 = fmaf(xr[d + 2], e1[d + 2], b2);
      b3 = fmaf(xr[d + 3], e1[d + 3], b3);
    }
    const float dot0 = (a0 + a1) + (a2 + a3);
    const float dot1 = (b0 + b1) + (b2 + b3);
    const float dist0 = fmaf(-2.0f, dot0, e2[k]);
    const float dist1 = fmaf(-2.0f, dot1, e2[k + 1]);
    // strict '<' keeps the FIRST minimum (matches jnp.argmin tie rule)
    bool c0 = dist0 < best; best = c0 ? dist0 : best; bi = c0 ? k : bi;
    bool c1 = dist1 < best; best = c1 ? dist1 : best; bi = c1 ? (k + 1) : bi;
    // interleave encodings zero-fill under the FMA work (nontemporal: don't
    // pollute L2 where the codebook lives)
    if (it < ZSTORES_PER_THREAD) {
      __builtin_nontemporal_store(zz, zdst + (size_t)it * 256 + tid);
    }
  }
  mind[(size_t)sp * N_ROWS + row] = best;
  midx[(size_t)sp * N_ROWS + row] = bi;
}

// ---------------- per-row finalize: combine splits, scatter, gather, reduce ----------------
__global__ __launch_bounds__(64) void vq_finalize_rows_kernel(
    const float* __restrict__ x, const float* __restrict__ cb,
    const float* __restrict__ mind, const int* __restrict__ midx,
    int* __restrict__ hist, float* __restrict__ lossSum,
    float* __restrict__ outp) {
  const int row = blockIdx.x * 64 + threadIdx.x;

  float best = 3.4e38f;
  int bi = 0;
#pragma unroll
  for (int s = 0; s < SPLITS; ++s) {
    const float d = mind[(size_t)s * N_ROWS + row];
    const int   i = midx[(size_t)s * N_ROWS + row];
    // ascending split order + strict '<' preserves first-min (lowest k)
    bool c = d < best; best = c ? d : best; bi = c ? i : bi;
  }

  atomicAdd(hist + bi, 1);
  outp[(size_t)OFF_E + (size_t)row * K_CODES + bi] = 1.0f;

  const float4* ecb = reinterpret_cast<const float4*>(cb + ((size_t)bi << 6));
  const float4* xv  = reinterpret_cast<const float4*>(x + ((size_t)row << 6));
  float* q = outp + OFF_Q + (size_t)row * DIM;  // only 4B-aligned -> scalar stores
  float ls = 0.f;
#pragma unroll
  for (int i = 0; i < DIM / 4; ++i) {
    const float4 ev = ecb[i];
    const float4 xw = xv[i];
    q[i * 4 + 0] = ev.x;
    q[i * 4 + 1] = ev.y;
    q[i * 4 + 2] = ev.z;
    q[i * 4 + 3] = ev.w;
    const float d0 = ev.x - xw.x, d1 = ev.y - xw.y;
    const float d2 = ev.z - xw.z, d3 = ev.w - xw.w;
    ls = fmaf(d0, d0, ls);
    ls = fmaf(d1, d1, ls);
    ls = fmaf(d2, d2, ls);
    ls = fmaf(d3, d3, ls);
  }
  // wave-64 reduction, one atomic per block
#pragma unroll
  for (int off = 32; off > 0; off >>= 1) ls += __shfl_down(ls, off, 64);
  if (threadIdx.x == 0) atomicAdd(lossSum, ls);
}

// ---------------- scalars: loss + perplexity ----------------
__global__ __launch_bounds__(256) void vq_scalars_kernel(
    const int* __restrict__ hist, const float* __restrict__ lossSum,
    float* __restrict__ outp) {
  __shared__ float red[256];
  float s = 0.f;
  for (int k = threadIdx.x; k < K_CODES; k += 256) {
    const float p = (float)hist[k] * (1.0f / (float)N_ROWS);
    s += p * logf(p + 1e-10f);
  }
  red[threadIdx.x] = s;
  __syncthreads();
  for (int off = 128; off > 0; off >>= 1) {
    if (threadIdx.x < off) red[threadIdx.x] += red[threadIdx.x + off];
    __syncthreads();
  }
  if (threadIdx.x == 0) {
    outp[OFF_P] = expf(-red[0]);
    outp[OFF_LOSS] = 0.25f * lossSum[0] * (1.0f / 1048576.0f);
  }
}

extern "C" void kernel_launch(void* const* d_in, const int* in_sizes, int n_in,
                              void* d_out, int out_size, void* d_ws, size_t ws_size,
                              hipStream_t stream) {
  const float* x  = (const float*)d_in[0];   // [16384, 64]
  const float* cb = (const float*)d_in[1];   // [8192, 64]
  float* outp = (float*)d_out;

  char* wsb = (char*)d_ws;
  float* e2      = (float*)(wsb + WS_E2);
  float* mind    = (float*)(wsb + WS_MIND);
  int*   midx    = (int*)  (wsb + WS_MIDX);
  int*   hist    = (int*)  (wsb + WS_HIST);
  float* lossSum = (float*)(wsb + WS_LOSS);

  // zero histogram + loss accumulator (ws is poisoned, not re-poisoned between replays)
  (void)hipMemsetAsync(hist, 0, K_CODES * sizeof(int) + sizeof(float), stream);

  vq_sqnorm_kernel<<<K_CODES / 256, 256, 0, stream>>>(cb, e2);
  vq_argmin_kernel<<<dim3(RB, SPLITS), 256, 0, stream>>>(x, cb, e2, mind, midx, outp);
  vq_finalize_rows_kernel<<<N_ROWS / 64, 64, 0, stream>>>(x, cb, mind, midx, hist, lossSum, outp);
  vq_scalars_kernel<<<1, 256, 0, stream>>>(hist, lossSum, outp);
}

// Round 3
// 300.089 us; speedup vs baseline: 2.4654x; 2.4654x over previous
//
#include <hip/hip_runtime.h>
#include <math.h>

// Problem constants (match reference)
#define N_ROWS   16384            // 32*512
#define DIM      64
#define K_CODES  8192
#define SPLITS   32
#define KC       (K_CODES / SPLITS)   // 256 codes per split
#define ROWS_PB  512                  // rows per block (2 per thread)
#define RB       (N_ROWS / ROWS_PB)   // 32 row-blocks
#define CHUNK    64                   // codes per LDS chunk (16 KB)
#define NCHUNK   (KC / CHUNK)         // 4

// Output layout (flat float32): loss | quantized | perplexity | encodings
#define OFF_LOSS 0
#define OFF_Q    1
#define OFF_P    1048577
#define OFF_E    1048578
#define ZBASE    1048576              // 16B-aligned base for bulk zero-fill
#define ENC_F4_TOTAL 33554432ULL      // 134217728 floats / 4
#define NBLOCKS  (RB * SPLITS)        // 1024
#define ZF4_PER_BLOCK (ENC_F4_TOTAL / NBLOCKS)      // 32768 float4 per block
#define ZSTORES_PER_THREAD (ZF4_PER_BLOCK / 256)    // 128 per thread

// native clang vector type (works with __builtin_nontemporal_store)
typedef float vfloat4 __attribute__((ext_vector_type(4)));

// Workspace layout (bytes)
#define WS_E2    0                          // 8192 floats = 32 KB
#define WS_MIND  32768                      // SPLITS*N floats = 2 MiB
#define WS_MIDX  (32768 + 2097152)          // SPLITS*N ints  = 2 MiB
#define WS_HIST  (32768 + 2097152 + 2097152)        // 8192 ints = 32 KB
#define WS_LOSS  (32768 + 2097152 + 2097152 + 32768) // 1 float

// ---------------- codebook squared norms ----------------
__global__ __launch_bounds__(256) void vq_sqnorm_kernel(
    const float* __restrict__ cb, float* __restrict__ e2) {
  const int k = blockIdx.x * 256 + threadIdx.x;
  const float4* e = reinterpret_cast<const float4*>(cb + ((size_t)k << 6));
  float s0 = 0.f, s1 = 0.f, s2 = 0.f, s3 = 0.f;
#pragma unroll
  for (int i = 0; i < DIM / 4; ++i) {
    float4 v = e[i];
    s0 = fmaf(v.x, v.x, s0);
    s1 = fmaf(v.y, v.y, s1);
    s2 = fmaf(v.z, v.z, s2);
    s3 = fmaf(v.w, v.w, s3);
  }
  e2[k] = (s0 + s1) + (s2 + s3);
}

// ---------------- main argmin: LDS-staged codebook, 2 rows/thread ----------------
__global__ __launch_bounds__(256) void vq_argmin_kernel(
    const float* __restrict__ x, const float* __restrict__ cb,
    const float* __restrict__ e2g, float* __restrict__ mind,
    int* __restrict__ midx, float* __restrict__ outp) {
  const int tid = threadIdx.x;
  const int rb  = blockIdx.x;   // row-block  [0,32)
  const int sp  = blockIdx.y;   // K split    [0,32)
  const int k0  = sp * KC;
  const int blin = sp * RB + rb;          // [0,1024)

  __shared__ float e_lds[CHUNK * DIM];    // 16 KB: one chunk of codes
  __shared__ float e2_lds[KC];            // 1 KB: this split's ||e||^2

  // stage split's squared norms (barrier below covers it)
  e2_lds[tid] = e2g[k0 + tid];            // KC == 256 == blockDim

  // two rows per thread, fully in registers (128 VGPRs)
  const int row0 = rb * ROWS_PB + tid;
  const int row1 = row0 + 256;
  float xr0[DIM], xr1[DIM];
  {
    const float4* xv0 = reinterpret_cast<const float4*>(x + ((size_t)row0 << 6));
    const float4* xv1 = reinterpret_cast<const float4*>(x + ((size_t)row1 << 6));
#pragma unroll
    for (int i = 0; i < DIM / 4; ++i) {
      reinterpret_cast<float4*>(xr0)[i] = xv0[i];
      reinterpret_cast<float4*>(xr1)[i] = xv1[i];
    }
  }

  // fused encodings zero-fill (nontemporal; 128 float4 per thread)
  vfloat4* zdst = reinterpret_cast<vfloat4*>(outp + ZBASE) + (size_t)blin * ZF4_PER_BLOCK + tid;
  const vfloat4 zz = (vfloat4)(0.0f);
  int zi = 0;
  if (blin == 0 && tid == 0) {
    outp[135266304] = 0.0f;   // two tail floats beyond the float4 bulk region
    outp[135266305] = 0.0f;
  }

  float best0 = 3.4e38f, best1 = 3.4e38f;
  int bi0 = 0, bi1 = 0;

  for (int ch = 0; ch < NCHUNK; ++ch) {
    // ---- stage CHUNK codes into LDS (reg-staged, coalesced f4) ----
    {
      const float4* gs = reinterpret_cast<const float4*>(cb + ((size_t)(k0 + ch * CHUNK) << 6));
      float4* lb = reinterpret_cast<float4*>(e_lds);
#pragma unroll
      for (int i = 0; i < 4; ++i) lb[i * 256 + tid] = gs[i * 256 + tid];
    }
    __syncthreads();

    // ---- sweep the 64 staged codes ----
#pragma unroll 2
    for (int c = 0; c < CHUNK; ++c) {
      const float4* ef = reinterpret_cast<const float4*>(e_lds + c * DIM);
      float a0 = 0.f, a1 = 0.f, a2 = 0.f, a3 = 0.f;
      float b0 = 0.f, b1 = 0.f, b2 = 0.f, b3 = 0.f;
#pragma unroll
      for (int d4 = 0; d4 < DIM / 4; ++d4) {
        const float4 ev = ef[d4];   // uniform broadcast ds_read_b128
        a0 = fmaf(xr0[4 * d4 + 0], ev.x, a0);
        a1 = fmaf(xr0[4 * d4 + 1], ev.y, a1);
        a2 = fmaf(xr0[4 * d4 + 2], ev.z, a2);
        a3 = fmaf(xr0[4 * d4 + 3], ev.w, a3);
        b0 = fmaf(xr1[4 * d4 + 0], ev.x, b0);
        b1 = fmaf(xr1[4 * d4 + 1], ev.y, b1);
        b2 = fmaf(xr1[4 * d4 + 2], ev.z, b2);
        b3 = fmaf(xr1[4 * d4 + 3], ev.w, b3);
      }
      const float e2k = e2_lds[ch * CHUNK + c];
      const int   k   = k0 + ch * CHUNK + c;
      const float dist0 = fmaf(-2.0f, (a0 + a1) + (a2 + a3), e2k);
      const float dist1 = fmaf(-2.0f, (b0 + b1) + (b2 + b3), e2k);
      // strict '<' keeps the FIRST minimum (matches jnp.argmin tie rule)
      bool c0 = dist0 < best0; best0 = c0 ? dist0 : best0; bi0 = c0 ? k : bi0;
      bool c1 = dist1 < best1; best1 = c1 ? dist1 : best1; bi1 = c1 ? k : bi1;
      // one nontemporal zero-store per 2 codes -> exactly 128 per thread
      if (c & 1) {
        __builtin_nontemporal_store(zz, zdst + (size_t)zi * 256);
        ++zi;
      }
    }
    __syncthreads();   // before next chunk overwrites e_lds
  }

  mind[(size_t)sp * N_ROWS + row0] = best0;
  midx[(size_t)sp * N_ROWS + row0] = bi0;
  mind[(size_t)sp * N_ROWS + row1] = best1;
  midx[(size_t)sp * N_ROWS + row1] = bi1;
}

// ---------------- per-row finalize: combine splits, scatter, gather, reduce ----------------
__global__ __launch_bounds__(64) void vq_finalize_rows_kernel(
    const float* __restrict__ x, const float* __restrict__ cb,
    const float* __restrict__ mind, const int* __restrict__ midx,
    int* __restrict__ hist, float* __restrict__ lossSum,
    float* __restrict__ outp) {
  const int row = blockIdx.x * 64 + threadIdx.x;

  float best = 3.4e38f;
  int bi = 0;
#pragma unroll
  for (int s = 0; s < SPLITS; ++s) {
    const float d = mind[(size_t)s * N_ROWS + row];
    const int   i = midx[(size_t)s * N_ROWS + row];
    // ascending split order + strict '<' preserves first-min (lowest k)
    bool c = d < best; best = c ? d : best; bi = c ? i : bi;
  }

  atomicAdd(hist + bi, 1);
  outp[(size_t)OFF_E + (size_t)row * K_CODES + bi] = 1.0f;

  const float4* ecb = reinterpret_cast<const float4*>(cb + ((size_t)bi << 6));
  const float4* xv  = reinterpret_cast<const float4*>(x + ((size_t)row << 6));
  float* q = outp + OFF_Q + (size_t)row * DIM;  // only 4B-aligned -> scalar stores
  float ls = 0.f;
#pragma unroll
  for (int i = 0; i < DIM / 4; ++i) {
    const float4 ev = ecb[i];
    const float4 xw = xv[i];
    q[i * 4 + 0] = ev.x;
    q[i * 4 + 1] = ev.y;
    q[i * 4 + 2] = ev.z;
    q[i * 4 + 3] = ev.w;
    const float d0 = ev.x - xw.x, d1 = ev.y - xw.y;
    const float d2 = ev.z - xw.z, d3 = ev.w - xw.w;
    ls = fmaf(d0, d0, ls);
    ls = fmaf(d1, d1, ls);
    ls = fmaf(d2, d2, ls);
    ls = fmaf(d3, d3, ls);
  }
  // wave-64 reduction, one atomic per block
#pragma unroll
  for (int off = 32; off > 0; off >>= 1) ls += __shfl_down(ls, off, 64);
  if (threadIdx.x == 0) atomicAdd(lossSum, ls);
}

// ---------------- scalars: loss + perplexity ----------------
__global__ __launch_bounds__(256) void vq_scalars_kernel(
    const int* __restrict__ hist, const float* __restrict__ lossSum,
    float* __restrict__ outp) {
  __shared__ float red[256];
  float s = 0.f;
  for (int k = threadIdx.x; k < K_CODES; k += 256) {
    const float p = (float)hist[k] * (1.0f / (float)N_ROWS);
    s += p * logf(p + 1e-10f);
  }
  red[threadIdx.x] = s;
  __syncthreads();
  for (int off = 128; off > 0; off >>= 1) {
    if (threadIdx.x < off) red[threadIdx.x] += red[threadIdx.x + off];
    __syncthreads();
  }
  if (threadIdx.x == 0) {
    outp[OFF_P] = expf(-red[0]);
    outp[OFF_LOSS] = 0.25f * lossSum[0] * (1.0f / 1048576.0f);
  }
}

extern "C" void kernel_launch(void* const* d_in, const int* in_sizes, int n_in,
                              void* d_out, int out_size, void* d_ws, size_t ws_size,
                              hipStream_t stream) {
  const float* x  = (const float*)d_in[0];   // [16384, 64]
  const float* cb = (const float*)d_in[1];   // [8192, 64]
  float* outp = (float*)d_out;

  char* wsb = (char*)d_ws;
  float* e2      = (float*)(wsb + WS_E2);
  float* mind    = (float*)(wsb + WS_MIND);
  int*   midx    = (int*)  (wsb + WS_MIDX);
  int*   hist    = (int*)  (wsb + WS_HIST);
  float* lossSum = (float*)(wsb + WS_LOSS);

  // zero histogram + loss accumulator (ws is poisoned, not re-poisoned between replays)
  (void)hipMemsetAsync(hist, 0, K_CODES * sizeof(int) + sizeof(float), stream);

  vq_sqnorm_kernel<<<K_CODES / 256, 256, 0, stream>>>(cb, e2);
  vq_argmin_kernel<<<dim3(RB, SPLITS), 256, 0, stream>>>(x, cb, e2, mind, midx, outp);
  vq_finalize_rows_kernel<<<N_ROWS / 64, 64, 0, stream>>>(x, cb, mind, midx, hist, lossSum, outp);
  vq_scalars_kernel<<<1, 256, 0, stream>>>(hist, lossSum, outp);
}

// Round 5
// 146.019 us; speedup vs baseline: 5.0667x; 2.0551x over previous
//
#include <hip/hip_runtime.h>
#include <math.h>

// Problem constants
#define N_ROWS   16384            // 32*512
#define DIM      64
#define K_CODES  8192
#define SPLITS   8
#define KC       (K_CODES / SPLITS)   // 1024 codes per split
#define CH       64                   // codes per LDS chunk
#define NCHUNK   (KC / CH)            // 16
#define CSTRIDE  200                  // ushorts per code row in cs (400 B; 192 data + 8 pad)

// Output layout (flat float32): loss | quantized | perplexity | encodings
#define OFF_LOSS 0
#define OFF_Q    1
#define OFF_P    1048577
#define OFF_E    1048578
#define ZBASE    1048576              // 16B-aligned base for bulk zero-fill
#define ENC_F4_TOTAL 33554432ULL      // 134217728 floats / 4
#define NBLK     1024                 // 128 row-blocks x 8 splits
#define ZF4_PER_BLOCK (ENC_F4_TOTAL / NBLK)   // 32768 float4 per block (128/thread)

// Workspace layout (bytes); total ~3.47 MB (< round-3's proven 4.26 MB)
#define WS_CS    0                              // 8192*200*2 = 3276800
#define WS_E2H   3276800                        // 8192 f32 = 32768
#define WS_KEY   (3276800 + 32768)              // 16384 u64 = 131072
#define WS_HIST  (3276800 + 32768 + 131072)     // 8192 int = 32768
#define WS_LOSS  (3276800 + 32768 + 131072 + 32768)

using bf16x8 = __attribute__((ext_vector_type(8))) short;
using f32x16 = __attribute__((ext_vector_type(16))) float;
typedef float vfloat4 __attribute__((ext_vector_type(4)));

static __device__ __forceinline__ unsigned short f2bf(float f) {
  unsigned int u = __float_as_uint(f);
  u = u + 0x7FFFu + ((u >> 16) & 1u);   // round-to-nearest-even
  return (unsigned short)(u >> 16);
}
static __device__ __forceinline__ float bf2f(unsigned short h) {
  return __uint_as_float(((unsigned int)h) << 16);
}

// ---------------- codebook 3-way bf16 split into padded layout cs[code][s*64+d] ----------------
__global__ __launch_bounds__(256) void vq_csplit_kernel(
    const float* __restrict__ cb, unsigned short* __restrict__ cs) {
  const int gid = blockIdx.x * 256 + threadIdx.x;   // 65536 total
  const int code = gid >> 3;
  const int dq = (gid & 7) << 3;                    // 8 d-elements per thread
  const float* s = cb + (size_t)code * 64 + dq;
  const float4 a = *(const float4*)s;
  const float4 b = *(const float4*)(s + 4);
  const float v[8] = {a.x, a.y, a.z, a.w, b.x, b.y, b.z, b.w};
  union { unsigned short u[8]; uint4 q; } h1, h2, h3;
#pragma unroll
  for (int j = 0; j < 8; ++j) {
    const float f = v[j];
    const unsigned short b1 = f2bf(f);  const float r  = f - bf2f(b1);
    const unsigned short b2 = f2bf(r);  const float r2 = r - bf2f(b2);
    const unsigned short b3 = f2bf(r2);
    h1.u[j] = b1; h2.u[j] = b2; h3.u[j] = b3;
  }
  unsigned short* base = cs + (size_t)code * CSTRIDE;
  *(uint4*)(base + 0 * 64 + dq) = h1.q;   // byte = code*400 + s*128 + dq*2 -> 16B aligned
  *(uint4*)(base + 1 * 64 + dq) = h2.q;
  *(uint4*)(base + 2 * 64 + dq) = h3.q;
}

// ---------------- e2h = -0.5 * ||e||^2 (exact fp32) ----------------
__global__ __launch_bounds__(256) void vq_sqnorm_kernel(
    const float* __restrict__ cb, float* __restrict__ e2h) {
  const int k = blockIdx.x * 256 + threadIdx.x;
  const float4* e = reinterpret_cast<const float4*>(cb + ((size_t)k << 6));
  float s0 = 0.f, s1 = 0.f, s2 = 0.f, s3 = 0.f;
#pragma unroll
  for (int i = 0; i < DIM / 4; ++i) {
    float4 v = e[i];
    s0 = fmaf(v.x, v.x, s0);
    s1 = fmaf(v.y, v.y, s1);
    s2 = fmaf(v.z, v.z, s2);
    s3 = fmaf(v.w, v.w, s3);
  }
  e2h[k] = -0.5f * ((s0 + s1) + (s2 + s3));
}

// ---------------- MFMA argmin: 6-pass bf16-split, fused encodings zero-fill ----------------
// Block: 256 thr = 4 waves, each wave owns 32 x-rows; sweeps KC codes of its split.
// acc' = dot(x,e) - ||e||^2/2 ; argmin dist == argmax acc' (dist' = -2*acc', can be <0!).
__global__ __launch_bounds__(256, 2) void vq_argmin_kernel(
    const float* __restrict__ x, const unsigned short* __restrict__ cs,
    const float* __restrict__ e2h, unsigned long long* __restrict__ rowkey,
    float* __restrict__ outp) {
  const int tid  = threadIdx.x;
  const int lane = tid & 63, wave = tid >> 6;
  const int g    = lane >> 5, c32 = lane & 31;
  const int sp   = blockIdx.y;
  const int k0   = sp * KC;
  const int myrow = blockIdx.x * 128 + wave * 32 + c32;

  __shared__ __align__(16) unsigned short Alds[CH * CSTRIDE];   // 25600 B
  __shared__ float e2l[KC];                                     // 4096 B

  // stage this split's -e2/2 (covered by the first __syncthreads below)
#pragma unroll
  for (int i = 0; i < KC / 256; ++i) e2l[i * 256 + tid] = e2h[k0 + i * 256 + tid];

  // B-side (x) fragments: 3 splits x 4 k-steps, register-resident (48 VGPRs).
  // lane -> (col = c32 = x-row, k-chunk = g*8..g*8+7 within each 16-k step).
  bf16x8 xf[3][4];
  {
    const float* xp = x + ((size_t)myrow << 6);
#pragma unroll
    for (int t = 0; t < 4; ++t) {
      const float* p = xp + t * 16 + g * 8;
      const float4 a = *(const float4*)p;
      const float4 b = *(const float4*)(p + 4);
      const float v[8] = {a.x, a.y, a.z, a.w, b.x, b.y, b.z, b.w};
      union { unsigned short u[8]; bf16x8 f; } u1, u2, u3;
#pragma unroll
      for (int j = 0; j < 8; ++j) {
        const float f = v[j];
        const unsigned short b1 = f2bf(f);  const float r  = f - bf2f(b1);
        const unsigned short b2 = f2bf(r);  const float r2 = r - bf2f(b2);
        const unsigned short b3 = f2bf(r2);
        u1.u[j] = b1; u2.u[j] = b2; u3.u[j] = b3;
      }
      xf[0][t] = u1.f; xf[1][t] = u2.f; xf[2][t] = u3.f;
    }
  }

  // fused encodings zero-fill setup (nontemporal; 128 float4/thread)
  const int blin = blockIdx.y * gridDim.x + blockIdx.x;
  vfloat4* zdst = (vfloat4*)(outp + ZBASE) + (size_t)blin * ZF4_PER_BLOCK + tid;
  const vfloat4 zz = (vfloat4)(0.0f);
  if (blockIdx.x == 0 && blockIdx.y == 0 && tid == 0) {
    outp[135266304] = 0.0f;   // two tail floats beyond the float4 bulk region
    outp[135266305] = 0.0f;
  }

  float best = -3.4e38f;   // argmax of acc'
  int   bi   = 0;

  for (int ch = 0; ch < NCHUNK; ++ch) {
    // stage CH codes (contiguous 25600 B block copy, 1600 x 16B chunks)
    {
      const uint4* src = (const uint4*)(cs + (size_t)(k0 + ch * CH) * CSTRIDE);
      uint4* dst = (uint4*)Alds;
#pragma unroll
      for (int j = 0; j < 7; ++j) {
        const int idx = j * 256 + tid;
        if (idx < (CH * CSTRIDE * 2) / 16) dst[idx] = src[idx];
      }
    }
    __syncthreads();

#pragma unroll
    for (int kt = 0; kt < 2; ++kt) {          // two 32-code tiles per chunk
      const int cl = ch * CH + kt * 32;       // code base within split
      // acc init = -e2/2 for the 16 codes this lane accumulates:
      // C row(code) = (reg&3) + 8*(reg>>2) + 4*g  (reg = 4q+r)
      f32x16 acc;
#pragma unroll
      for (int q = 0; q < 4; ++q) {
        const float4 e4 = *(const float4*)(e2l + cl + q * 8 + g * 4);
        acc[4 * q + 0] = e4.x; acc[4 * q + 1] = e4.y;
        acc[4 * q + 2] = e4.z; acc[4 * q + 3] = e4.w;
      }
      // A-side (codes) fragments from LDS: row = c32, k-chunk = g*8 (same map as B)
      const unsigned short* ab = Alds + (size_t)(kt * 32 + c32) * CSTRIDE + g * 8;
      bf16x8 af0[4], af1[4], af2[4];
#pragma unroll
      for (int t = 0; t < 4; ++t) {
        af0[t] = *(const bf16x8*)(ab + 0 * 64 + t * 16);
        af1[t] = *(const bf16x8*)(ab + 1 * 64 + t * 16);
        af2[t] = *(const bf16x8*)(ab + 2 * 64 + t * 16);
      }
      // 6 split-products x 4 k-steps = 24 MFMA, all into one accumulator.
      // dropped terms (x2e3, x3e2, x3e3) are <= 2^-24 relative: fp32-level.
#pragma unroll
      for (int t = 0; t < 4; ++t) {
        acc = __builtin_amdgcn_mfma_f32_32x32x16_bf16(af0[t], xf[0][t], acc, 0, 0, 0);
        acc = __builtin_amdgcn_mfma_f32_32x32x16_bf16(af1[t], xf[0][t], acc, 0, 0, 0);
        acc = __builtin_amdgcn_mfma_f32_32x32x16_bf16(af0[t], xf[1][t], acc, 0, 0, 0);
        acc = __builtin_amdgcn_mfma_f32_32x32x16_bf16(af1[t], xf[1][t], acc, 0, 0, 0);
        acc = __builtin_amdgcn_mfma_f32_32x32x16_bf16(af2[t], xf[0][t], acc, 0, 0, 0);
        acc = __builtin_amdgcn_mfma_f32_32x32x16_bf16(af0[t], xf[2][t], acc, 0, 0, 0);
      }
      // epilogue: running argmax; codes ascending within lane (first-max == first-min of dist)
      const int cg = k0 + cl + 4 * g;
#pragma unroll
      for (int q = 0; q < 4; ++q) {
#pragma unroll
        for (int r = 0; r < 4; ++r) {
          const float v = acc[4 * q + r];
          const int code = cg + 8 * q + r;
          const bool c = v > best;
          best = c ? v : best;
          bi   = c ? code : bi;
        }
      }
    }
    // fused zero-fill: 8 nontemporal stores per chunk per thread
#pragma unroll
    for (int u = 0; u < 8; ++u)
      __builtin_nontemporal_store(zz, zdst + (size_t)(ch * 8 + u) * 256);
    __syncthreads();   // before next chunk overwrites Alds
  }

  // combine the two half-code-sets (lanes l and l^32 share x-row = lane&31)
  const float ob = __shfl_xor(best, 32, 64);
  const int   oi = __shfl_xor(bi,   32, 64);
  if (ob > best || (ob == best && oi < bi)) { best = ob; bi = oi; }
  if (lane < 32) {
    const float dist = -2.0f * best;   // = ||x-e||^2 - ||x||^2 : CAN be negative!
    // bijective monotone float->uint transform (fixes round-4 sign bug):
    // positives: set sign bit (order kept); negatives: flip all bits (order fixed,
    // and they sort below all positives). unsigned order == float order.
    unsigned int db = __float_as_uint(dist);
    db ^= (unsigned int)((int)db >> 31) | 0x80000000u;
    const unsigned long long key = ((unsigned long long)db << 32) | (unsigned int)bi;
    atomicMin(rowkey + myrow, key);    // min key == (min dist, then min code): jnp tie rule
  }
}

// ---------------- per-row finalize: scatter, gather, loss ----------------
__global__ __launch_bounds__(64) void vq_finalize_rows_kernel(
    const float* __restrict__ x, const float* __restrict__ cb,
    const unsigned long long* __restrict__ rowkey,
    int* __restrict__ hist, float* __restrict__ lossSum,
    float* __restrict__ outp) {
  const int row = blockIdx.x * 64 + threadIdx.x;
  const int bi = (int)(rowkey[row] & 0xFFFFFFFFull);

  atomicAdd(hist + bi, 1);
  outp[(size_t)OFF_E + (size_t)row * K_CODES + bi] = 1.0f;

  const float4* ecb = reinterpret_cast<const float4*>(cb + ((size_t)bi << 6));
  const float4* xv  = reinterpret_cast<const float4*>(x + ((size_t)row << 6));
  float* q = outp + OFF_Q + (size_t)row * DIM;  // only 4B-aligned -> scalar stores
  float ls = 0.f;
#pragma unroll
  for (int i = 0; i < DIM / 4; ++i) {
    const float4 ev = ecb[i];
    const float4 xw = xv[i];
    q[i * 4 + 0] = ev.x;
    q[i * 4 + 1] = ev.y;
    q[i * 4 + 2] = ev.z;
    q[i * 4 + 3] = ev.w;
    const float d0 = ev.x - xw.x, d1 = ev.y - xw.y;
    const float d2 = ev.z - xw.z, d3 = ev.w - xw.w;
    ls = fmaf(d0, d0, ls);
    ls = fmaf(d1, d1, ls);
    ls = fmaf(d2, d2, ls);
    ls = fmaf(d3, d3, ls);
  }
#pragma unroll
  for (int off = 32; off > 0; off >>= 1) ls += __shfl_down(ls, off, 64);
  if (threadIdx.x == 0) atomicAdd(lossSum, ls);
}

// ---------------- scalars: loss + perplexity ----------------
__global__ __launch_bounds__(256) void vq_scalars_kernel(
    const int* __restrict__ hist, const float* __restrict__ lossSum,
    float* __restrict__ outp) {
  __shared__ float red[256];
  float s = 0.f;
  for (int k = threadIdx.x; k < K_CODES; k += 256) {
    const float p = (float)hist[k] * (1.0f / (float)N_ROWS);
    s += p * logf(p + 1e-10f);
  }
  red[threadIdx.x] = s;
  __syncthreads();
  for (int off = 128; off > 0; off >>= 1) {
    if (threadIdx.x < off) red[threadIdx.x] += red[threadIdx.x + off];
    __syncthreads();
  }
  if (threadIdx.x == 0) {
    outp[OFF_P] = expf(-red[0]);
    outp[OFF_LOSS] = 0.25f * lossSum[0] * (1.0f / 1048576.0f);
  }
}

extern "C" void kernel_launch(void* const* d_in, const int* in_sizes, int n_in,
                              void* d_out, int out_size, void* d_ws, size_t ws_size,
                              hipStream_t stream) {
  const float* x  = (const float*)d_in[0];   // [16384, 64]
  const float* cb = (const float*)d_in[1];   // [8192, 64]
  float* outp = (float*)d_out;

  char* wsb = (char*)d_ws;
  unsigned short* cs          = (unsigned short*)(wsb + WS_CS);
  float* e2h                  = (float*)(wsb + WS_E2H);
  unsigned long long* rowkey  = (unsigned long long*)(wsb + WS_KEY);
  int*   hist                 = (int*)(wsb + WS_HIST);
  float* lossSum              = (float*)(wsb + WS_LOSS);

  // init: rowkey -> all-ones (u64 max), hist+loss -> 0 (ws not re-poisoned between replays)
  (void)hipMemsetAsync(rowkey, 0xFF, N_ROWS * sizeof(unsigned long long), stream);
  (void)hipMemsetAsync(hist, 0, K_CODES * sizeof(int) + sizeof(float), stream);

  vq_csplit_kernel<<<256, 256, 0, stream>>>(cb, cs);
  vq_sqnorm_kernel<<<K_CODES / 256, 256, 0, stream>>>(cb, e2h);
  vq_argmin_kernel<<<dim3(128, SPLITS), 256, 0, stream>>>(x, cs, e2h, rowkey, outp);
  vq_finalize_rows_kernel<<<N_ROWS / 64, 64, 0, stream>>>(x, cb, rowkey, hist, lossSum, outp);
  vq_scalars_kernel<<<1, 256, 0, stream>>>(hist, lossSum, outp);
}